// Round 2
// baseline (375.994 us; speedup 1.0000x reference)
//
#include <hip/hip_runtime.h>
#include <hip/hip_fp16.h>
#include <cstdint>
#include <cstddef>

constexpr int R  = 512;
constexpr int C  = 16;
constexpr int HW = R * R;
constexpr int NBINS = 4096;   // 4-bit cells per axis, 3D Morton

// ---------------------------------------------------------------------------
// Transpose (C,H,W) fp32 -> (H,W,C) fp16. Coalesced reads per channel,
// LDS tile (stride 17) for conflict-free, coalesced packed half2 writes.
// grid = (R, R/64, 3), block = 256
// ---------------------------------------------------------------------------
__global__ __launch_bounds__(256) void transpose_chw_hwc_h(
    const float* __restrict__ p0, const float* __restrict__ p1,
    const float* __restrict__ p2, __half* __restrict__ dst)
{
    __shared__ float lds[64 * 17];
    const int y  = blockIdx.x;
    const int x0 = blockIdx.y * 64;
    const int pl = blockIdx.z;
    const float* src = (pl == 0) ? p0 : ((pl == 1) ? p1 : p2);
    const int tid = threadIdx.x;
    const int xl  = tid & 63;
    const int c0  = tid >> 6;
#pragma unroll
    for (int i = 0; i < 4; ++i) {
        const int c = c0 * 4 + i;
        lds[xl * 17 + c] = src[c * HW + y * R + x0 + xl];
    }
    __syncthreads();
    __half2* dbase = (__half2*)(dst + ((size_t)pl * HW + (size_t)(y * R + x0)) * C);
#pragma unroll
    for (int i = 0; i < 2; ++i) {
        const int j  = tid + i * 256;   // half2 index, 0..511
        const int e0 = 2 * j;           // even element: same texel as e0+1
        const float a = lds[(e0 >> 4) * 17 + (e0 & 15)];
        const float b = lds[(e0 >> 4) * 17 + ((e0 & 15) + 1)];
        dbase[j] = __floats2half2_rn(a, b);
    }
}

__device__ __forceinline__ uint32_t morton_key(float xv0, float xv1, float xv2)
{
    // px in [0,511] for x in [-1,1]; cell = floor(px)/32 in [0,15]
    const float s = 0.5f * (float)(R - 1);
    int c0 = (int)((xv0 + 1.0f) * s); c0 = min(max(c0, 0), R - 1); c0 >>= 5;
    int c1 = (int)((xv1 + 1.0f) * s); c1 = min(max(c1, 0), R - 1); c1 >>= 5;
    int c2 = (int)((xv2 + 1.0f) * s); c2 = min(max(c2, 0), R - 1); c2 >>= 5;
    uint32_t k = 0;
#pragma unroll
    for (int i = 0; i < 4; ++i) {
        k |= ((uint32_t)((c0 >> i) & 1)) << (3 * i + 2);
        k |= ((uint32_t)((c1 >> i) & 1)) << (3 * i + 1);
        k |= ((uint32_t)((c2 >> i) & 1)) << (3 * i + 0);
    }
    return k;
}

__global__ __launch_bounds__(256) void hist_pts(
    const float* __restrict__ x, unsigned int* __restrict__ counts, int B)
{
    const int p = blockIdx.x * 256 + threadIdx.x;
    if (p >= B) return;
    const float a = x[(size_t)p * 3 + 0];
    const float b = x[(size_t)p * 3 + 1];
    const float c = x[(size_t)p * 3 + 2];
    atomicAdd(&counts[morton_key(a, b, c)], 1u);
}

// Exclusive scan of 4096 counts -> cursor. One block, 1024 threads, 4/thread.
__global__ __launch_bounds__(1024) void scan4096(
    const unsigned int* __restrict__ counts, unsigned int* __restrict__ cursor)
{
    __shared__ unsigned int s[1024];
    const int t = threadIdx.x;
    const unsigned int c0 = counts[4 * t + 0];
    const unsigned int c1 = counts[4 * t + 1];
    const unsigned int c2 = counts[4 * t + 2];
    const unsigned int c3 = counts[4 * t + 3];
    const unsigned int tot = c0 + c1 + c2 + c3;
    unsigned int v = tot;
    s[t] = v;
    __syncthreads();
    for (int off = 1; off < 1024; off <<= 1) {
        const unsigned int u = (t >= off) ? s[t - off] : 0u;
        __syncthreads();
        v += u;
        s[t] = v;
        __syncthreads();
    }
    const unsigned int excl = v - tot;
    cursor[4 * t + 0] = excl;
    cursor[4 * t + 1] = excl + c0;
    cursor[4 * t + 2] = excl + c0 + c1;
    cursor[4 * t + 3] = excl + c0 + c1 + c2;
}

__global__ __launch_bounds__(256) void scatter_pts(
    const float* __restrict__ x, unsigned int* __restrict__ cursor,
    int4* __restrict__ recs, int B)
{
    const int p = blockIdx.x * 256 + threadIdx.x;
    if (p >= B) return;
    const float a = x[(size_t)p * 3 + 0];
    const float b = x[(size_t)p * 3 + 1];
    const float c = x[(size_t)p * 3 + 2];
    const uint32_t key = morton_key(a, b, c);
    const unsigned int pos = atomicAdd(&cursor[key], 1u);
    recs[pos] = make_int4(__float_as_int(a), __float_as_int(b), __float_as_int(c), p);
}

__device__ __forceinline__ void load_h8(const __half* addr, float f[8])
{
    const int4 v = *(const int4*)addr;          // 16B = 8 halves
    const __half2* h = (const __half2*)&v;
#pragma unroll
    for (int i = 0; i < 4; ++i) {
        const float2 t2 = __half22float2(h[i]);
        f[2 * i + 0] = t2.x;
        f[2 * i + 1] = t2.y;
    }
}

// ---------------------------------------------------------------------------
// Sample sorted records from fp16 (H,W,C) planes; scatter result to out[orig].
// 2 lanes per point: lane owns 8 channels (16B per corner load).
// XCD-bijective block remap keeps each XCD on a contiguous Morton range.
// ---------------------------------------------------------------------------
__global__ __launch_bounds__(256) void sample_sorted(
    const int4* __restrict__ recs, const __half* __restrict__ t,
    float* __restrict__ out, int B, int q, int r)
{
    const uint32_t bid  = blockIdx.x;
    const uint32_t xcd  = bid & 7u;
    const uint32_t slot = bid >> 3;
    const uint32_t base = (xcd < (uint32_t)r) ? xcd * (q + 1)
                                              : (uint32_t)r * (q + 1) + (xcd - r) * q;
    const uint32_t lb   = base + slot;

    const int tid = (int)(lb * 256u + threadIdx.x);
    const int p   = tid >> 1;
    const int h   = tid & 1;
    if (p >= B) return;

    const int4 rec = recs[p];
    const float xv0 = __int_as_float(rec.x);
    const float xv1 = __int_as_float(rec.y);
    const float xv2 = __int_as_float(rec.z);
    const int orig  = rec.w;

    const float gxs[3] = { xv0, xv0, xv1 };
    const float gys[3] = { xv1, xv2, xv2 };

    float acc[8] = {1.f, 1.f, 1.f, 1.f, 1.f, 1.f, 1.f, 1.f};

#pragma unroll
    for (int pl = 0; pl < 3; ++pl) {
        const float gx = gxs[pl], gy = gys[pl];
        const float px = (gx + 1.0f) * 0.5f * (float)(R - 1);
        const float py = (gy + 1.0f) * 0.5f * (float)(R - 1);
        const float x0f = floorf(px), y0f = floorf(py);
        const float wx = px - x0f,   wy = py - y0f;
        int x0 = (int)x0f; x0 = min(max(x0, 0), R - 1);
        int y0 = (int)y0f; y0 = min(max(y0, 0), R - 1);
        const int x1 = min(x0 + 1, R - 1);
        const int y1 = min(y0 + 1, R - 1);

        const __half* pb = t + (size_t)pl * (size_t)(HW * C) + h * 8;
        float f00[8], f01[8], f10[8], f11[8];
        load_h8(pb + (size_t)(y0 * R + x0) * C, f00);
        load_h8(pb + (size_t)(y0 * R + x1) * C, f01);
        load_h8(pb + (size_t)(y1 * R + x0) * C, f10);
        load_h8(pb + (size_t)(y1 * R + x1) * C, f11);

        const float w00 = (1.f - wx) * (1.f - wy);
        const float w01 = wx * (1.f - wy);
        const float w10 = (1.f - wx) * wy;
        const float w11 = wx * wy;

#pragma unroll
        for (int k = 0; k < 8; ++k) {
            acc[k] *= f00[k] * w00 + f01[k] * w01 + f10[k] * w10 + f11[k] * w11;
        }
    }

    float* o = out + (size_t)orig * C + h * 8;
    *(float4*)(o + 0) = make_float4(acc[0], acc[1], acc[2], acc[3]);
    *(float4*)(o + 4) = make_float4(acc[4], acc[5], acc[6], acc[7]);
}

// ============================ fp32 fallback path ============================
__global__ __launch_bounds__(256) void transpose_chw_hwc(
    const float* __restrict__ p0, const float* __restrict__ p1,
    const float* __restrict__ p2, float* __restrict__ dst)
{
    __shared__ float lds[64 * 17];
    const int y  = blockIdx.x;
    const int x0 = blockIdx.y * 64;
    const int pl = blockIdx.z;
    const float* src = (pl == 0) ? p0 : ((pl == 1) ? p1 : p2);
    const int tid = threadIdx.x;
    const int xl  = tid & 63;
    const int c0  = tid >> 6;
#pragma unroll
    for (int i = 0; i < 4; ++i) {
        const int c = c0 * 4 + i;
        lds[xl * 17 + c] = src[c * HW + y * R + x0 + xl];
    }
    __syncthreads();
    float* dbase = dst + ((size_t)pl * HW + (size_t)(y * R + x0)) * C;
#pragma unroll
    for (int i = 0; i < 4; ++i) {
        const int j = tid + i * 256;
        dbase[j] = lds[(j >> 4) * 17 + (j & 15)];
    }
}

__global__ __launch_bounds__(256) void sample_hwc(
    const float* __restrict__ x, const float* __restrict__ t,
    float* __restrict__ out, int B)
{
    const int tid = blockIdx.x * 256 + threadIdx.x;
    const int p   = tid >> 2;
    const int cg  = tid & 3;
    if (p >= B) return;

    const float xv0 = x[(size_t)p * 3 + 0];
    const float xv1 = x[(size_t)p * 3 + 1];
    const float xv2 = x[(size_t)p * 3 + 2];
    const float gxs[3] = { xv0, xv0, xv1 };
    const float gys[3] = { xv1, xv2, xv2 };
    float4 acc = make_float4(1.f, 1.f, 1.f, 1.f);

#pragma unroll
    for (int pl = 0; pl < 3; ++pl) {
        const float gx = gxs[pl], gy = gys[pl];
        const float px = (gx + 1.0f) * 0.5f * (float)(R - 1);
        const float py = (gy + 1.0f) * 0.5f * (float)(R - 1);
        const float x0f = floorf(px), y0f = floorf(py);
        const float wx = px - x0f,   wy = py - y0f;
        int x0 = (int)x0f; x0 = min(max(x0, 0), R - 1);
        int y0 = (int)y0f; y0 = min(max(y0, 0), R - 1);
        const int x1 = min(x0 + 1, R - 1);
        const int y1 = min(y0 + 1, R - 1);

        const float* pb = t + (size_t)pl * (size_t)(HW * C) + cg * 4;
        const float4 p00 = *(const float4*)(pb + (size_t)(y0 * R + x0) * C);
        const float4 p01 = *(const float4*)(pb + (size_t)(y0 * R + x1) * C);
        const float4 p10 = *(const float4*)(pb + (size_t)(y1 * R + x0) * C);
        const float4 p11 = *(const float4*)(pb + (size_t)(y1 * R + x1) * C);

        const float w00 = (1.f - wx) * (1.f - wy);
        const float w01 = wx * (1.f - wy);
        const float w10 = (1.f - wx) * wy;
        const float w11 = wx * wy;

        float4 f;
        f.x = p00.x * w00 + p01.x * w01 + p10.x * w10 + p11.x * w11;
        f.y = p00.y * w00 + p01.y * w01 + p10.y * w10 + p11.y * w11;
        f.z = p00.z * w00 + p01.z * w01 + p10.z * w10 + p11.z * w11;
        f.w = p00.w * w00 + p01.w * w01 + p10.w * w10 + p11.w * w11;

        acc.x *= f.x; acc.y *= f.y; acc.z *= f.z; acc.w *= f.w;
    }

    *(float4*)(out + (size_t)p * C + cg * 4) = acc;
}

__global__ __launch_bounds__(256) void sample_chw(
    const float* __restrict__ x,
    const float* __restrict__ p0, const float* __restrict__ p1,
    const float* __restrict__ p2, float* __restrict__ out, int B)
{
    const int tid = blockIdx.x * 256 + threadIdx.x;
    const int p   = tid >> 2;
    const int cg  = tid & 3;
    if (p >= B) return;
    const float xv0 = x[(size_t)p * 3 + 0];
    const float xv1 = x[(size_t)p * 3 + 1];
    const float xv2 = x[(size_t)p * 3 + 2];
    const float gxs[3] = { xv0, xv0, xv1 };
    const float gys[3] = { xv1, xv2, xv2 };
    const float* planes[3] = { p0, p1, p2 };
    float acc[4] = {1.f, 1.f, 1.f, 1.f};
#pragma unroll
    for (int pl = 0; pl < 3; ++pl) {
        const float gx = gxs[pl], gy = gys[pl];
        const float px = (gx + 1.0f) * 0.5f * (float)(R - 1);
        const float py = (gy + 1.0f) * 0.5f * (float)(R - 1);
        const float x0f = floorf(px), y0f = floorf(py);
        const float wx = px - x0f,   wy = py - y0f;
        int x0 = (int)x0f; x0 = min(max(x0, 0), R - 1);
        int y0 = (int)y0f; y0 = min(max(y0, 0), R - 1);
        const int x1 = min(x0 + 1, R - 1);
        const int y1 = min(y0 + 1, R - 1);
        const float w00 = (1.f - wx) * (1.f - wy);
        const float w01 = wx * (1.f - wy);
        const float w10 = (1.f - wx) * wy;
        const float w11 = wx * wy;
        const float* pb = planes[pl];
#pragma unroll
        for (int k = 0; k < 4; ++k) {
            const int c = cg * 4 + k;
            const float* b2 = pb + (size_t)c * HW;
            const float v00 = b2[y0 * R + x0];
            const float v01 = b2[y0 * R + x1];
            const float v10 = b2[y1 * R + x0];
            const float v11 = b2[y1 * R + x1];
            acc[k] *= v00 * w00 + v01 * w01 + v10 * w10 + v11 * w11;
        }
    }
    float* o = out + (size_t)p * C + cg * 4;
    o[0] = acc[0]; o[1] = acc[1]; o[2] = acc[2]; o[3] = acc[3];
}

// ===========================================================================
extern "C" void kernel_launch(void* const* d_in, const int* in_sizes, int n_in,
                              void* d_out, int out_size, void* d_ws, size_t ws_size,
                              hipStream_t stream) {
    const float* x  = (const float*)d_in[0];
    const float* p0 = (const float*)d_in[1];
    const float* p1 = (const float*)d_in[2];
    const float* p2 = (const float*)d_in[3];
    float* out = (float*)d_out;
    const int B = in_sizes[0] / 3;

    // workspace layout for full path
    const size_t t_bytes    = (size_t)3 * HW * C * sizeof(__half);     // 24 MiB
    const size_t recs_bytes = (size_t)B * 16;                          // 32 MB (B=2M)
    const size_t cnt_bytes  = (size_t)NBINS * 4;
    const size_t off_t      = 0;
    const size_t off_recs   = (t_bytes + 255) & ~(size_t)255;
    const size_t off_counts = (off_recs + recs_bytes + 255) & ~(size_t)255;
    const size_t off_cursor = (off_counts + cnt_bytes + 255) & ~(size_t)255;
    const size_t need_full  = off_cursor + cnt_bytes;

    const size_t need_fp32  = (size_t)3 * HW * C * sizeof(float);      // 48 MiB

    if (d_ws != nullptr && ws_size >= need_full) {
        __half*       t      = (__half*)((char*)d_ws + off_t);
        int4*         recs   = (int4*)((char*)d_ws + off_recs);
        unsigned int* counts = (unsigned int*)((char*)d_ws + off_counts);
        unsigned int* cursor = (unsigned int*)((char*)d_ws + off_cursor);

        dim3 tg(R, R / 64, 3);
        transpose_chw_hwc_h<<<tg, 256, 0, stream>>>(p0, p1, p2, t);

        hipMemsetAsync(counts, 0, cnt_bytes, stream);
        const int nblkP = (B + 255) / 256;
        hist_pts<<<nblkP, 256, 0, stream>>>(x, counts, B);
        scan4096<<<1, 1024, 0, stream>>>(counts, cursor);
        scatter_pts<<<nblkP, 256, 0, stream>>>(x, cursor, recs, B);

        const int nthr2 = B * 2;
        const int nblk2 = (nthr2 + 255) / 256;
        const int q = nblk2 / 8, r = nblk2 % 8;
        sample_sorted<<<nblk2, 256, 0, stream>>>(recs, t, out, B, q, r);
    } else if (d_ws != nullptr && ws_size >= need_fp32) {
        float* t = (float*)d_ws;
        dim3 tg(R, R / 64, 3);
        transpose_chw_hwc<<<tg, 256, 0, stream>>>(p0, p1, p2, t);
        const int nthr = B * 4;
        const int nblk = (nthr + 255) / 256;
        sample_hwc<<<nblk, 256, 0, stream>>>(x, t, out, B);
    } else {
        const int nthr = B * 4;
        const int nblk = (nthr + 255) / 256;
        sample_chw<<<nblk, 256, 0, stream>>>(x, p0, p1, p2, out, B);
    }
}

// Round 3
// 254.578 us; speedup vs baseline: 1.4769x; 1.4769x over previous
//
#include <hip/hip_runtime.h>
#include <hip/hip_fp16.h>
#include <cstdint>
#include <cstddef>

constexpr int R  = 512;
constexpr int C  = 16;
constexpr int HW = R * R;
constexpr int NBINS = 4096;   // 4-bit cells per axis, 3D Morton
constexpr int NPART = 8;      // XCD partitions (blockIdx & 7 heuristic)
constexpr int NCNT  = NBINS * NPART;

typedef float v4f __attribute__((ext_vector_type(4)));
typedef int   v4i __attribute__((ext_vector_type(4)));

// ---------------------------------------------------------------------------
// Transpose (C,H,W) fp32 -> (H,W,C) fp16. Coalesced reads per channel,
// LDS tile (stride 17) conflict-free, coalesced packed half2 writes.
// grid = (R, R/64, 3), block = 256
// ---------------------------------------------------------------------------
__global__ __launch_bounds__(256) void transpose_chw_hwc_h(
    const float* __restrict__ p0, const float* __restrict__ p1,
    const float* __restrict__ p2, __half* __restrict__ dst)
{
    __shared__ float lds[64 * 17];
    const int y  = blockIdx.x;
    const int x0 = blockIdx.y * 64;
    const int pl = blockIdx.z;
    const float* src = (pl == 0) ? p0 : ((pl == 1) ? p1 : p2);
    const int tid = threadIdx.x;
    const int xl  = tid & 63;
    const int c0  = tid >> 6;
#pragma unroll
    for (int i = 0; i < 4; ++i) {
        const int c = c0 * 4 + i;
        lds[xl * 17 + c] = src[c * HW + y * R + x0 + xl];
    }
    __syncthreads();
    __half2* dbase = (__half2*)(dst + ((size_t)pl * HW + (size_t)(y * R + x0)) * C);
#pragma unroll
    for (int i = 0; i < 2; ++i) {
        const int j  = tid + i * 256;   // half2 index, 0..511
        const int e0 = 2 * j;
        const float a = lds[(e0 >> 4) * 17 + (e0 & 15)];
        const float b = lds[(e0 >> 4) * 17 + ((e0 & 15) + 1)];
        dbase[j] = __floats2half2_rn(a, b);
    }
}

__device__ __forceinline__ uint32_t morton_key(float xv0, float xv1, float xv2)
{
    const float s = 0.5f * (float)(R - 1);
    int c0 = (int)((xv0 + 1.0f) * s); c0 = min(max(c0, 0), R - 1); c0 >>= 5;
    int c1 = (int)((xv1 + 1.0f) * s); c1 = min(max(c1, 0), R - 1); c1 >>= 5;
    int c2 = (int)((xv2 + 1.0f) * s); c2 = min(max(c2, 0), R - 1); c2 >>= 5;
    uint32_t k = 0;
#pragma unroll
    for (int i = 0; i < 4; ++i) {
        k |= ((uint32_t)((c0 >> i) & 1)) << (3 * i + 2);
        k |= ((uint32_t)((c1 >> i) & 1)) << (3 * i + 1);
        k |= ((uint32_t)((c2 >> i) & 1)) << (3 * i + 0);
    }
    return k;
}

// Counters laid out part-major: counts[part*NBINS + key]. All atomics to a
// given counter line come from one partition (= one XCD by round-robin
// heuristic) -> no cross-XCD line ping-pong.
__global__ __launch_bounds__(256) void hist_pts(
    const float* __restrict__ x, unsigned int* __restrict__ counts, int B)
{
    const int p = blockIdx.x * 256 + threadIdx.x;
    if (p >= B) return;
    const float a = x[(size_t)p * 3 + 0];
    const float b = x[(size_t)p * 3 + 1];
    const float c = x[(size_t)p * 3 + 2];
    const uint32_t key = morton_key(a, b, c);
    atomicAdd(&counts[(blockIdx.x & (NPART - 1)) * NBINS + key], 1u);
}

// Exclusive scan over 32768 counters in LOGICAL order (key,part) — i.e. the
// records array is bin-major — while counters live part-major in memory.
// One block, 1024 threads, 32 logical entries each.
__global__ __launch_bounds__(1024) void scan_counts(
    const unsigned int* __restrict__ counts, unsigned int* __restrict__ cursor)
{
    __shared__ unsigned int s[1024];
    const int t = threadIdx.x;
    unsigned int v[32];
    unsigned int sum = 0;
#pragma unroll
    for (int i = 0; i < 32; ++i) {
        const int L = t * 32 + i;             // logical = key*NPART + part
        const int key = L >> 3, part = L & 7;
        v[i] = counts[part * NBINS + key];
        sum += v[i];
    }
    unsigned int run = 0;
#pragma unroll
    for (int i = 0; i < 32; ++i) { const unsigned int tmp = v[i]; v[i] = run; run += tmp; }
    s[t] = sum;
    __syncthreads();
    unsigned int incl = sum;
    for (int off = 1; off < 1024; off <<= 1) {
        const unsigned int u = (t >= off) ? s[t - off] : 0u;
        __syncthreads();
        incl += u;
        s[t] = incl;
        __syncthreads();
    }
    const unsigned int excl = incl - sum;
#pragma unroll
    for (int i = 0; i < 32; ++i) {
        const int L = t * 32 + i;
        const int key = L >> 3, part = L & 7;
        cursor[part * NBINS + key] = excl + v[i];
    }
}

__global__ __launch_bounds__(256) void scatter_pts(
    const float* __restrict__ x, unsigned int* __restrict__ cursor,
    int4* __restrict__ recs, int B)
{
    const int p = blockIdx.x * 256 + threadIdx.x;
    if (p >= B) return;
    const float a = x[(size_t)p * 3 + 0];
    const float b = x[(size_t)p * 3 + 1];
    const float c = x[(size_t)p * 3 + 2];
    const uint32_t key = morton_key(a, b, c);
    const unsigned int pos =
        atomicAdd(&cursor[(blockIdx.x & (NPART - 1)) * NBINS + key], 1u);
    recs[pos] = make_int4(__float_as_int(a), __float_as_int(b), __float_as_int(c), p);
}

__device__ __forceinline__ void load_h8(const __half* addr, float f[8])
{
    const int4 v = *(const int4*)addr;          // 16B = 8 halves
    const __half2* h = (const __half2*)&v;
#pragma unroll
    for (int i = 0; i < 4; ++i) {
        const float2 t2 = __half22float2(h[i]);
        f[2 * i + 0] = t2.x;
        f[2 * i + 1] = t2.y;
    }
}

// ---------------------------------------------------------------------------
// Sample sorted (bin-major) records from fp16 (H,W,C) planes; scatter result
// to out[orig]. 2 lanes per point (8 channels each). XCD-bijective block
// remap gives XCD j a contiguous record slice ~= Morton octant j, so each
// XCD's plane working set is ~6MB. recs/out use non-temporal accesses so the
// 160MB stream doesn't evict plane lines from L2.
// ---------------------------------------------------------------------------
__global__ __launch_bounds__(256) void sample_sorted(
    const int4* __restrict__ recs, const __half* __restrict__ t,
    float* __restrict__ out, int B, int q, int r)
{
    const uint32_t bid  = blockIdx.x;
    const uint32_t xcd  = bid & 7u;
    const uint32_t slot = bid >> 3;
    const uint32_t base = (xcd < (uint32_t)r) ? xcd * (q + 1)
                                              : (uint32_t)r * (q + 1) + (xcd - r) * q;
    const uint32_t lb   = base + slot;

    const int tid = (int)(lb * 256u + threadIdx.x);
    const int p   = tid >> 1;
    const int h   = tid & 1;
    if (p >= B) return;

    const v4i rec = __builtin_nontemporal_load((const v4i*)&recs[p]);
    const float xv0 = __int_as_float(rec.x);
    const float xv1 = __int_as_float(rec.y);
    const float xv2 = __int_as_float(rec.z);
    const int orig  = rec.w;

    const float gxs[3] = { xv0, xv0, xv1 };
    const float gys[3] = { xv1, xv2, xv2 };

    float acc[8] = {1.f, 1.f, 1.f, 1.f, 1.f, 1.f, 1.f, 1.f};

#pragma unroll
    for (int pl = 0; pl < 3; ++pl) {
        const float gx = gxs[pl], gy = gys[pl];
        const float px = (gx + 1.0f) * 0.5f * (float)(R - 1);
        const float py = (gy + 1.0f) * 0.5f * (float)(R - 1);
        const float x0f = floorf(px), y0f = floorf(py);
        const float wx = px - x0f,   wy = py - y0f;
        int x0 = (int)x0f; x0 = min(max(x0, 0), R - 1);
        int y0 = (int)y0f; y0 = min(max(y0, 0), R - 1);
        const int x1 = min(x0 + 1, R - 1);
        const int y1 = min(y0 + 1, R - 1);

        const __half* pb = t + (size_t)pl * (size_t)(HW * C) + h * 8;
        float f00[8], f01[8], f10[8], f11[8];
        load_h8(pb + (size_t)(y0 * R + x0) * C, f00);
        load_h8(pb + (size_t)(y0 * R + x1) * C, f01);
        load_h8(pb + (size_t)(y1 * R + x0) * C, f10);
        load_h8(pb + (size_t)(y1 * R + x1) * C, f11);

        const float w00 = (1.f - wx) * (1.f - wy);
        const float w01 = wx * (1.f - wy);
        const float w10 = (1.f - wx) * wy;
        const float w11 = wx * wy;

#pragma unroll
        for (int k = 0; k < 8; ++k) {
            acc[k] *= f00[k] * w00 + f01[k] * w01 + f10[k] * w10 + f11[k] * w11;
        }
    }

    float* o = out + (size_t)orig * C + h * 8;
    const v4f o0 = { acc[0], acc[1], acc[2], acc[3] };
    const v4f o1 = { acc[4], acc[5], acc[6], acc[7] };
    __builtin_nontemporal_store(o0, (v4f*)(o + 0));
    __builtin_nontemporal_store(o1, (v4f*)(o + 4));
}

// ============================ fallback paths ================================
__global__ __launch_bounds__(256) void transpose_chw_hwc(
    const float* __restrict__ p0, const float* __restrict__ p1,
    const float* __restrict__ p2, float* __restrict__ dst)
{
    __shared__ float lds[64 * 17];
    const int y  = blockIdx.x;
    const int x0 = blockIdx.y * 64;
    const int pl = blockIdx.z;
    const float* src = (pl == 0) ? p0 : ((pl == 1) ? p1 : p2);
    const int tid = threadIdx.x;
    const int xl  = tid & 63;
    const int c0  = tid >> 6;
#pragma unroll
    for (int i = 0; i < 4; ++i) {
        const int c = c0 * 4 + i;
        lds[xl * 17 + c] = src[c * HW + y * R + x0 + xl];
    }
    __syncthreads();
    float* dbase = dst + ((size_t)pl * HW + (size_t)(y * R + x0)) * C;
#pragma unroll
    for (int i = 0; i < 4; ++i) {
        const int j = tid + i * 256;
        dbase[j] = lds[(j >> 4) * 17 + (j & 15)];
    }
}

__global__ __launch_bounds__(256) void sample_hwc(
    const float* __restrict__ x, const float* __restrict__ t,
    float* __restrict__ out, int B)
{
    const int tid = blockIdx.x * 256 + threadIdx.x;
    const int p   = tid >> 2;
    const int cg  = tid & 3;
    if (p >= B) return;

    const float xv0 = x[(size_t)p * 3 + 0];
    const float xv1 = x[(size_t)p * 3 + 1];
    const float xv2 = x[(size_t)p * 3 + 2];
    const float gxs[3] = { xv0, xv0, xv1 };
    const float gys[3] = { xv1, xv2, xv2 };
    float4 acc = make_float4(1.f, 1.f, 1.f, 1.f);

#pragma unroll
    for (int pl = 0; pl < 3; ++pl) {
        const float gx = gxs[pl], gy = gys[pl];
        const float px = (gx + 1.0f) * 0.5f * (float)(R - 1);
        const float py = (gy + 1.0f) * 0.5f * (float)(R - 1);
        const float x0f = floorf(px), y0f = floorf(py);
        const float wx = px - x0f,   wy = py - y0f;
        int x0 = (int)x0f; x0 = min(max(x0, 0), R - 1);
        int y0 = (int)y0f; y0 = min(max(y0, 0), R - 1);
        const int x1 = min(x0 + 1, R - 1);
        const int y1 = min(y0 + 1, R - 1);

        const float* pb = t + (size_t)pl * (size_t)(HW * C) + cg * 4;
        const float4 p00 = *(const float4*)(pb + (size_t)(y0 * R + x0) * C);
        const float4 p01 = *(const float4*)(pb + (size_t)(y0 * R + x1) * C);
        const float4 p10 = *(const float4*)(pb + (size_t)(y1 * R + x0) * C);
        const float4 p11 = *(const float4*)(pb + (size_t)(y1 * R + x1) * C);

        const float w00 = (1.f - wx) * (1.f - wy);
        const float w01 = wx * (1.f - wy);
        const float w10 = (1.f - wx) * wy;
        const float w11 = wx * wy;

        float4 f;
        f.x = p00.x * w00 + p01.x * w01 + p10.x * w10 + p11.x * w11;
        f.y = p00.y * w00 + p01.y * w01 + p10.y * w10 + p11.y * w11;
        f.z = p00.z * w00 + p01.z * w01 + p10.z * w10 + p11.z * w11;
        f.w = p00.w * w00 + p01.w * w01 + p10.w * w10 + p11.w * w11;

        acc.x *= f.x; acc.y *= f.y; acc.z *= f.z; acc.w *= f.w;
    }

    *(float4*)(out + (size_t)p * C + cg * 4) = acc;
}

__global__ __launch_bounds__(256) void sample_chw(
    const float* __restrict__ x,
    const float* __restrict__ p0, const float* __restrict__ p1,
    const float* __restrict__ p2, float* __restrict__ out, int B)
{
    const int tid = blockIdx.x * 256 + threadIdx.x;
    const int p   = tid >> 2;
    const int cg  = tid & 3;
    if (p >= B) return;
    const float xv0 = x[(size_t)p * 3 + 0];
    const float xv1 = x[(size_t)p * 3 + 1];
    const float xv2 = x[(size_t)p * 3 + 2];
    const float gxs[3] = { xv0, xv0, xv1 };
    const float gys[3] = { xv1, xv2, xv2 };
    const float* planes[3] = { p0, p1, p2 };
    float acc[4] = {1.f, 1.f, 1.f, 1.f};
#pragma unroll
    for (int pl = 0; pl < 3; ++pl) {
        const float gx = gxs[pl], gy = gys[pl];
        const float px = (gx + 1.0f) * 0.5f * (float)(R - 1);
        const float py = (gy + 1.0f) * 0.5f * (float)(R - 1);
        const float x0f = floorf(px), y0f = floorf(py);
        const float wx = px - x0f,   wy = py - y0f;
        int x0 = (int)x0f; x0 = min(max(x0, 0), R - 1);
        int y0 = (int)y0f; y0 = min(max(y0, 0), R - 1);
        const int x1 = min(x0 + 1, R - 1);
        const int y1 = min(y0 + 1, R - 1);
        const float w00 = (1.f - wx) * (1.f - wy);
        const float w01 = wx * (1.f - wy);
        const float w10 = (1.f - wx) * wy;
        const float w11 = wx * wy;
        const float* pb = planes[pl];
#pragma unroll
        for (int k = 0; k < 4; ++k) {
            const int c = cg * 4 + k;
            const float* b2 = pb + (size_t)c * HW;
            const float v00 = b2[y0 * R + x0];
            const float v01 = b2[y0 * R + x1];
            const float v10 = b2[y1 * R + x0];
            const float v11 = b2[y1 * R + x1];
            acc[k] *= v00 * w00 + v01 * w01 + v10 * w10 + v11 * w11;
        }
    }
    float* o = out + (size_t)p * C + cg * 4;
    o[0] = acc[0]; o[1] = acc[1]; o[2] = acc[2]; o[3] = acc[3];
}

// ===========================================================================
extern "C" void kernel_launch(void* const* d_in, const int* in_sizes, int n_in,
                              void* d_out, int out_size, void* d_ws, size_t ws_size,
                              hipStream_t stream) {
    const float* x  = (const float*)d_in[0];
    const float* p0 = (const float*)d_in[1];
    const float* p1 = (const float*)d_in[2];
    const float* p2 = (const float*)d_in[3];
    float* out = (float*)d_out;
    const int B = in_sizes[0] / 3;

    const size_t t_bytes    = (size_t)3 * HW * C * sizeof(__half);     // 24 MiB
    const size_t recs_bytes = (size_t)B * 16;                          // 32 MB
    const size_t cnt_bytes  = (size_t)NCNT * 4;                        // 128 KiB
    const size_t off_t      = 0;
    const size_t off_recs   = (t_bytes + 255) & ~(size_t)255;
    const size_t off_counts = (off_recs + recs_bytes + 255) & ~(size_t)255;
    const size_t off_cursor = (off_counts + cnt_bytes + 255) & ~(size_t)255;
    const size_t need_full  = off_cursor + cnt_bytes;

    const size_t need_fp32  = (size_t)3 * HW * C * sizeof(float);      // 48 MiB

    if (d_ws != nullptr && ws_size >= need_full) {
        __half*       t      = (__half*)((char*)d_ws + off_t);
        int4*         recs   = (int4*)((char*)d_ws + off_recs);
        unsigned int* counts = (unsigned int*)((char*)d_ws + off_counts);
        unsigned int* cursor = (unsigned int*)((char*)d_ws + off_cursor);

        dim3 tg(R, R / 64, 3);
        transpose_chw_hwc_h<<<tg, 256, 0, stream>>>(p0, p1, p2, t);

        hipMemsetAsync(counts, 0, cnt_bytes, stream);
        const int nblkP = (B + 255) / 256;
        hist_pts<<<nblkP, 256, 0, stream>>>(x, counts, B);
        scan_counts<<<1, 1024, 0, stream>>>(counts, cursor);
        scatter_pts<<<nblkP, 256, 0, stream>>>(x, cursor, recs, B);

        const int nthr2 = B * 2;
        const int nblk2 = (nthr2 + 255) / 256;
        const int q = nblk2 / 8, r = nblk2 % 8;
        sample_sorted<<<nblk2, 256, 0, stream>>>(recs, t, out, B, q, r);
    } else if (d_ws != nullptr && ws_size >= need_fp32) {
        float* t = (float*)d_ws;
        dim3 tg(R, R / 64, 3);
        transpose_chw_hwc<<<tg, 256, 0, stream>>>(p0, p1, p2, t);
        const int nthr = B * 4;
        const int nblk = (nthr + 255) / 256;
        sample_hwc<<<nblk, 256, 0, stream>>>(x, t, out, B);
    } else {
        const int nthr = B * 4;
        const int nblk = (nthr + 255) / 256;
        sample_chw<<<nblk, 256, 0, stream>>>(x, p0, p1, p2, out, B);
    }
}